// Round 3
// baseline (47.428 us; speedup 1.0000x reference)
//
#include <hip/hip_runtime.h>
#include <hip/hip_bf16.h>

// out[b,s,d] = x[b,s,d] * (feature_rand[s] >= 0.2f ? 1 : 0)
// x: (128, 128, 2048) f32, feature_rand: (128,) f32.
// Memory-bound elementwise; float4 vectorized, wave-uniform row branch lets
// dropped rows skip the global read (store zeros only).
// Round 1 -> 2: nontemporal loads/stores (zero reuse; avoid L2 allocation).
// Round 2 -> 3: use clang ext_vector_type (nontemporal builtins reject
//               HIP_vector_type).

#define DROPOUT_PROB 0.2f

typedef float f32x4 __attribute__((ext_vector_type(4)));

__global__ void SpectralDropout_37254546325874_kernel(
    const f32x4* __restrict__ x,
    const float* __restrict__ feature_rand,
    f32x4* __restrict__ out,
    int n4)
{
    const int stride = gridDim.x * blockDim.x;
    for (int i = blockIdx.x * blockDim.x + threadIdx.x; i < n4; i += stride) {
        // 2048 floats per row = 512 float4 per row; 128 rows (s) per batch.
        const int s = (i >> 9) & 127;
        // Wave-uniform: 64 consecutive lanes stay within one 512-float4 row.
        const bool keep = feature_rand[s] >= DROPOUT_PROB;
        f32x4 v;
        if (keep) {
            v = __builtin_nontemporal_load(&x[i]);
        } else {
            v = (f32x4){0.0f, 0.0f, 0.0f, 0.0f};
        }
        __builtin_nontemporal_store(v, &out[i]);
    }
}

extern "C" void kernel_launch(void* const* d_in, const int* in_sizes, int n_in,
                              void* d_out, int out_size, void* d_ws, size_t ws_size,
                              hipStream_t stream) {
    const f32x4* x = (const f32x4*)d_in[0];
    const float* feature_rand = (const float*)d_in[1];
    f32x4* out = (f32x4*)d_out;

    const int n4 = out_size / 4;  // 33554432 / 4 = 8388608 float4s

    const int block = 256;
    const int grid = 2048;  // grid-stride; ~16 float4 per thread
    SpectralDropout_37254546325874_kernel<<<grid, block, 0, stream>>>(
        x, feature_rand, out, n4);
}

// Round 4
// 37.589 us; speedup vs baseline: 1.2617x; 1.2617x over previous
//
#include <hip/hip_runtime.h>
#include <hip/hip_bf16.h>

// out[b,s,d] = x[b,s,d] * (feature_rand[s] >= 0.2f ? 1 : 0)
// x: (128, 128, 2048) f32, feature_rand: (128,) f32.
// Memory-bound elementwise; float4 vectorized, wave-uniform row branch lets
// dropped rows skip the global read (store zeros only).
// Round 1: 37.7 us (~6.4 TB/s effective — above 6.29 TB/s copy ceiling).
// Round 2/3: nontemporal load/store REGRESSED to 47.4 us (-26%) — nt bypass
//            forfeits L2/L3 buffering on this write-heavy stream. Reverted.

#define DROPOUT_PROB 0.2f

__global__ void SpectralDropout_37254546325874_kernel(
    const float4* __restrict__ x,
    const float* __restrict__ feature_rand,
    float4* __restrict__ out,
    int n4)
{
    const int stride = gridDim.x * blockDim.x;
    for (int i = blockIdx.x * blockDim.x + threadIdx.x; i < n4; i += stride) {
        // 2048 floats per row = 512 float4 per row; 128 rows (s) per batch.
        const int s = (i >> 9) & 127;
        // Wave-uniform: 64 consecutive lanes stay within one 512-float4 row.
        const bool keep = feature_rand[s] >= DROPOUT_PROB;
        if (keep) {
            out[i] = x[i];
        } else {
            out[i] = make_float4(0.0f, 0.0f, 0.0f, 0.0f);
        }
    }
}

extern "C" void kernel_launch(void* const* d_in, const int* in_sizes, int n_in,
                              void* d_out, int out_size, void* d_ws, size_t ws_size,
                              hipStream_t stream) {
    const float4* x = (const float4*)d_in[0];
    const float* feature_rand = (const float*)d_in[1];
    float4* out = (float4*)d_out;

    const int n4 = out_size / 4;  // 33554432 / 4 = 8388608 float4s

    const int block = 256;
    const int grid = 2048;  // grid-stride; ~16 float4 per thread
    SpectralDropout_37254546325874_kernel<<<grid, block, 0, stream>>>(
        x, feature_rand, out, n4);
}